// Round 9
// baseline (511.471 us; speedup 1.0000x reference)
//
#include <hip/hip_runtime.h>
#include <hip/hip_bf16.h>
#include <stdint.h>

typedef __attribute__((ext_vector_type(4))) float f32x4;
typedef __attribute__((ext_vector_type(8))) short short8v;

typedef __attribute__((address_space(1))) void gvoid;
typedef __attribute__((address_space(3))) void lvoid;

#define GLD16(gp, lp) __builtin_amdgcn_global_load_lds((const gvoid*)(gp), (lvoid*)(lp), 16, 0, 0)

__device__ __forceinline__ unsigned short f2bf(float f) {
    union { float ff; unsigned uu; } a; a.ff = f;
    unsigned u = a.uu;
    u += 0x7FFFu + ((u >> 16) & 1u);   // RNE; inputs finite
    return (unsigned short)(u >> 16);
}

// ---- Ub[o][r] = bf16(U[o][r] * (S[r]+eps[r])), row-major [4096][4096] ----
__global__ __launch_bounds__(256) void prep_u_kernel(
    const float* __restrict__ U, const float* __restrict__ S,
    const float* __restrict__ eps, unsigned short* __restrict__ Ub) {
    long idx = ((long)blockIdx.x * 256 + threadIdx.x) * 8;
    int r = (int)(idx & 4095);
    f32x4 u0 = *(const f32x4*)(U + idx);
    f32x4 u1 = *(const f32x4*)(U + idx + 4);
    f32x4 s0 = *(const f32x4*)(S + r);
    f32x4 s1 = *(const f32x4*)(S + r + 4);
    f32x4 e0 = *(const f32x4*)(eps + r);
    f32x4 e1 = *(const f32x4*)(eps + r + 4);
    union { uint4 v; unsigned short s[8]; } o;
#pragma unroll
    for (int j = 0; j < 4; ++j) {
        o.s[j]     = f2bf(u0[j] * (s0[j] + e0[j]));
        o.s[j + 4] = f2bf(u1[j] * (s1[j] + e1[j]));
    }
    *(uint4*)(Ub + idx) = o.v;
}

// ---- generic fp32 -> bf16 convert, 8 elems/thread ----
__global__ __launch_bounds__(256) void cvt_bf16_kernel(
    const float* __restrict__ src, unsigned short* __restrict__ dst) {
    long idx = ((long)blockIdx.x * 256 + threadIdx.x) * 8;
    f32x4 v0 = *(const f32x4*)(src + idx);
    f32x4 v1 = *(const f32x4*)(src + idx + 4);
    union { uint4 v; unsigned short s[8]; } o;
#pragma unroll
    for (int j = 0; j < 4; ++j) {
        o.s[j]     = f2bf(v0[j]);
        o.s[j + 4] = f2bf(v1[j]);
    }
    *(uint4*)(dst + idx) = o.v;
}

// ---- VtT[k][r] = bf16(Vt[r][k]); 64x64 tiles, padded LDS (conflict-free) ----
__global__ __launch_bounds__(256) void transpose_cvt_kernel(
    const float* __restrict__ src, unsigned short* __restrict__ dst) {
    __shared__ float tile[64][65];
    int tx = threadIdx.x & 63;
    int tq = threadIdx.x >> 6;
    int r0 = blockIdx.y << 6;
    int k0 = blockIdx.x << 6;
#pragma unroll
    for (int i = 0; i < 16; ++i) {
        int row = (i << 2) + tq;
        tile[row][tx] = src[(long)(r0 + row) * 4096 + k0 + tx];
    }
    __syncthreads();
#pragma unroll
    for (int i = 0; i < 16; ++i) {
        int krow = (i << 2) + tq;
        dst[(long)(k0 + krow) * 4096 + r0 + tx] = f2bf(tile[tx][krow]);
    }
}

// =====================================================================
// 256x128-tile NT GEMM, BK=32, TRI-buffered LDS (72 KB) -> 2 blocks/CU.
// C[M][N] = A[M][K] * B[N][K]^T (+bias). bf16 in, fp32 acc.
// 512 thr = 8 waves as 4M x 2N, wave tile 64x64 (acc = 64 VGPR).
//
// Rationale (r6/r7/r8 evidence): barrier count / read-prefetch / phase
// merging all null-to-negative -> per-iter cost = MFMA + LDS traffic,
// nearly unoverlapped (1 block/CU, lockstep waves). Fix both terms:
//  - LDS read traffic: 4Mx2N waves on 256x128 tile = A-redund 2 (was 4)
//    + B-redund 4 on half-size B: 256 KB per K=128 (was 384 KB).
//  - Overlap: 72 KB LDS -> 2 blocks/CU; block B's MFMAs cover block A's
//    read/stage bursts (m103 mechanism). launch_bounds(512,4) caps
//    VGPR<=128 so both blocks co-reside (16 waves/CU).
// Ring: iter i reads buf[i%3], stages buf[(i+2)%3]; vmcnt(3) per iter
// -> staged buf drained one FULL iter before its first read (RAW ok);
// stage issues one barrier after the buffer's last read (WAR ok).
// Stage/swizzle addressing identical to the verified 0-conflict round-3
// pattern (A chunk = same [256][32] layout; B = its 128-row half).
// =====================================================================
#define MM(a, b, c) __builtin_amdgcn_mfma_f32_16x16x32_bf16(a, b, c, 0, 0, 0)

#define ACH(b) (As + (b) * 8192)    // 16 KB chunks
#define BCH(b) (Bs + (b) * 4096)    // 8 KB chunks

#define STAGE_A(b, koff) do { \
    const unsigned short* _s = A + gAr + (koff); \
    unsigned short* _d = ACH(b) + wave * 512; \
    GLD16(_s, _d); GLD16(_s + (long)128 * K, _d + 4096); } while (0)

#define STAGE_B(b, koff) do { \
    const unsigned short* _s = B + gBr + (koff); \
    unsigned short* _d = BCH(b) + wave * 512; \
    GLD16(_s, _d); } while (0)

#define LOAD_A(b) do { \
    const unsigned short* _p = ACH(b) + aBase; \
    _Pragma("unroll") \
    for (int _m = 0; _m < 4; ++_m) aR[_m] = *(const short8v*)(_p + _m * 512); } while (0)

#define READ_B(b) do { \
    const unsigned short* _p = BCH(b) + bBase; \
    _Pragma("unroll") \
    for (int _n = 0; _n < 4; ++_n) bR[_n] = *(const short8v*)(_p + _n * 512); } while (0)

#define PH_SYNC do { \
    __builtin_amdgcn_s_barrier(); \
    asm volatile("s_waitcnt lgkmcnt(0)" ::: "memory"); } while (0)

#define MFMA16 do { \
    __builtin_amdgcn_s_setprio(1); \
    _Pragma("unroll") \
    for (int _m = 0; _m < 4; ++_m) { \
        acc[_m][0] = MM(aR[_m], bR[0], acc[_m][0]); \
        acc[_m][1] = MM(aR[_m], bR[1], acc[_m][1]); \
        acc[_m][2] = MM(aR[_m], bR[2], acc[_m][2]); \
        acc[_m][3] = MM(aR[_m], bR[3], acc[_m][3]); \
    } \
    __builtin_amdgcn_s_setprio(0); } while (0)

#define VM3 asm volatile("s_waitcnt vmcnt(3)" ::: "memory")
#define PH_END __builtin_amdgcn_s_barrier()

// One K-step: read buf rb, stage buf sb at element-k offset sk.
#define ITER(rb, sb, sk) do { \
    LOAD_A(rb); READ_B(rb); \
    STAGE_A(sb, sk); STAGE_B(sb, sk); \
    PH_SYNC; MFMA16; VM3; PH_END; } while (0)

template<int OUT_BF16, int BIAS>
__global__ __launch_bounds__(512, 4) void gemm256_kernel(
    const unsigned short* __restrict__ A,   // [M][K] bf16 bits
    const unsigned short* __restrict__ B,   // [N][K] bf16 bits
    void* __restrict__ Cv, const float* __restrict__ bias,
    int M, int N, int K) {
    __shared__ unsigned short As[3 * 8192];   // 48 KB
    __shared__ unsigned short Bs[3 * 4096];   // 24 KB

    const int tid  = threadIdx.x;
    const int wave = tid >> 6;
    const int lane = tid & 63;
    const int fr   = lane & 15;
    const int fq   = lane >> 4;

    // XCD-aware bijective swizzle (nwg % 8 == 0 for all launches)
    const int nwg = gridDim.x;
    const int bid = blockIdx.x;
    const int cpx = nwg >> 3;
    const int wg  = (bid & 7) * cpx + (bid >> 3);
    const int ntn = N >> 7;                  // BN = 128
    const long m0 = (long)(wg / ntn) << 8;   // BM = 256
    const long n0 = (long)(wg % ntn) << 7;

    const int wwr = wave >> 1;   // 0..3  (M quarter)
    const int wwc = wave & 1;    // 0..1  (N half)

    // Stage addressing (verified pattern): A chunk [256 rows][32 k],
    // B chunk [128 rows][32 k]; global src slot = (si&3)^((row>>1)&3).
    const int  rS  = tid >> 2;                        // A rows rS,rS+128; B row rS
    const int  sS  = (tid & 3) ^ ((rS >> 1) & 3);
    const long gAr = (m0 + rS) * K + sS * 8;
    const long gBr = (n0 + rS) * K + sS * 8;

    // ds_read (swizzled): elem = row*32 + ((fq ^ ((row>>1)&3))*8)
    const int swz   = (fq ^ ((fr >> 1) & 3)) * 8;
    const int aBase = (wwr * 64 + fr) * 32 + swz;
    const int bBase = (wwc * 64 + fr) * 32 + swz;

    f32x4  acc[4][4] = {};
    short8v aR[4], bR[4];

    // Prologue: stage buf0@k0, buf1@k32; VM3 drains buf0's 3 loads.
    STAGE_A(0, 0);  STAGE_B(0, 0);
    STAGE_A(1, 32); STAGE_B(1, 32);
    VM3;
    __builtin_amdgcn_s_barrier();

    // K/32 = 128 iters = 42 groups of 3 + 2 tail.
    for (int g = 0; g < 42; ++g) {
        const int kb = 96 * g;
        ITER(0, 2, kb + 64);
        ITER(1, 0, kb + 96);
        ITER(2, 1, kb + 128);
    }
    // Tail: i=126 (buf0@4032), i=127 (buf1@4064); dead stages keep
    // the vmcnt ring uniform (k=0 reload, never read).
    ITER(0, 2, 0);
    ITER(1, 0, 0);

    // Epilogue: C/D layout col = lane&15, row = (lane>>4)*4 + j
#pragma unroll
    for (int nf = 0; nf < 4; ++nf) {
        const int col = (int)n0 + wwc * 64 + nf * 16 + fr;
        float bv = BIAS ? bias[col] : 0.0f;
#pragma unroll
        for (int mf = 0; mf < 4; ++mf) {
            f32x4 v = acc[mf][nf];
            long rowb = m0 + wwr * 64 + mf * 16 + fq * 4;
#pragma unroll
            for (int j = 0; j < 4; ++j) {
                float val = v[j] + bv;
                long off = (rowb + j) * N + col;
                if (OUT_BF16) ((unsigned short*)Cv)[off] = f2bf(val);
                else          ((float*)Cv)[off] = val;
            }
        }
    }
}

extern "C" void kernel_launch(void* const* d_in, const int* in_sizes, int n_in,
                              void* d_out, int out_size, void* d_ws, size_t ws_size,
                              hipStream_t stream) {
    const float* x    = (const float*)d_in[0];   // [4,2048,4096] = [8192][4096]
    const float* U    = (const float*)d_in[1];   // [4096][4096]
    const float* S    = (const float*)d_in[2];   // [4096]
    const float* Vt   = (const float*)d_in[3];   // [4096][4096]
    const float* eps  = (const float*)d_in[4];   // [4096]
    const float* bias = (const float*)d_in[5];   // [4096]
    float* out = (float*)d_out;                  // [8192][4096] fp32

    char* ws = (char*)d_ws;
    unsigned short* Ub  = (unsigned short*)(ws);                       // 32 MB
    unsigned short* VtT = (unsigned short*)(ws + (size_t)(32 << 20));  // 32 MB
    unsigned short* Wb  = (unsigned short*)(ws + (size_t)(64 << 20));  // 32 MB
    unsigned short* Xb  = (unsigned short*)(ws);  // 64 MB, reuses Ub+VtT after GEMM1

    // 1) Ub = bf16(U * (S+eps))            [o][r]
    prep_u_kernel<<<8192, 256, 0, stream>>>(U, S, eps, Ub);
    // 2) VtT = bf16(Vt^T)                  [k][r]
    transpose_cvt_kernel<<<dim3(64, 64), 256, 0, stream>>>(Vt, VtT);
    // 3) Wb[o][k] = Ub @ VtT^T             (NT, K=r)  -> 512 wg
    gemm256_kernel<1, 0><<<512, 512, 0, stream>>>(Ub, VtT, (void*)Wb, nullptr,
                                                  4096, 4096, 4096);
    // 4) Xb = bf16(x)                      [m][k]  (overwrites Ub/VtT — now dead)
    cvt_bf16_kernel<<<16384, 256, 0, stream>>>(x, Xb);
    // 5) out[m][o] = Xb @ Wb^T + bias      (NT, K=k)  -> 1024 wg
    gemm256_kernel<0, 1><<<1024, 512, 0, stream>>>(Xb, Wb, (void*)out, bias,
                                                   8192, 4096, 4096);
}

// Round 10
// 442.087 us; speedup vs baseline: 1.1569x; 1.1569x over previous
//
#include <hip/hip_runtime.h>
#include <hip/hip_bf16.h>
#include <stdint.h>

typedef __attribute__((ext_vector_type(4))) float f32x4;
typedef __attribute__((ext_vector_type(8))) short short8v;

typedef __attribute__((address_space(1))) void gvoid;
typedef __attribute__((address_space(3))) void lvoid;

#define GLD16(gp, lp) __builtin_amdgcn_global_load_lds((const gvoid*)(gp), (lvoid*)(lp), 16, 0, 0)

__device__ __forceinline__ unsigned short f2bf(float f) {
    union { float ff; unsigned uu; } a; a.ff = f;
    unsigned u = a.uu;
    u += 0x7FFFu + ((u >> 16) & 1u);   // RNE; inputs finite
    return (unsigned short)(u >> 16);
}

// ---- Ub[o][r] = bf16(U[o][r] * (S[r]+eps[r])), row-major [4096][4096] ----
__global__ __launch_bounds__(256) void prep_u_kernel(
    const float* __restrict__ U, const float* __restrict__ S,
    const float* __restrict__ eps, unsigned short* __restrict__ Ub) {
    long idx = ((long)blockIdx.x * 256 + threadIdx.x) * 8;
    int r = (int)(idx & 4095);
    f32x4 u0 = *(const f32x4*)(U + idx);
    f32x4 u1 = *(const f32x4*)(U + idx + 4);
    f32x4 s0 = *(const f32x4*)(S + r);
    f32x4 s1 = *(const f32x4*)(S + r + 4);
    f32x4 e0 = *(const f32x4*)(eps + r);
    f32x4 e1 = *(const f32x4*)(eps + r + 4);
    union { uint4 v; unsigned short s[8]; } o;
#pragma unroll
    for (int j = 0; j < 4; ++j) {
        o.s[j]     = f2bf(u0[j] * (s0[j] + e0[j]));
        o.s[j + 4] = f2bf(u1[j] * (s1[j] + e1[j]));
    }
    *(uint4*)(Ub + idx) = o.v;
}

// ---- generic fp32 -> bf16 convert, 8 elems/thread ----
__global__ __launch_bounds__(256) void cvt_bf16_kernel(
    const float* __restrict__ src, unsigned short* __restrict__ dst) {
    long idx = ((long)blockIdx.x * 256 + threadIdx.x) * 8;
    f32x4 v0 = *(const f32x4*)(src + idx);
    f32x4 v1 = *(const f32x4*)(src + idx + 4);
    union { uint4 v; unsigned short s[8]; } o;
#pragma unroll
    for (int j = 0; j < 4; ++j) {
        o.s[j]     = f2bf(v0[j]);
        o.s[j + 4] = f2bf(v1[j]);
    }
    *(uint4*)(dst + idx) = o.v;
}

// ---- VtT[k][r] = bf16(Vt[r][k]); 64x64 tiles, padded LDS (conflict-free) ----
__global__ __launch_bounds__(256) void transpose_cvt_kernel(
    const float* __restrict__ src, unsigned short* __restrict__ dst) {
    __shared__ float tile[64][65];
    int tx = threadIdx.x & 63;
    int tq = threadIdx.x >> 6;
    int r0 = blockIdx.y << 6;
    int k0 = blockIdx.x << 6;
#pragma unroll
    for (int i = 0; i < 16; ++i) {
        int row = (i << 2) + tq;
        tile[row][tx] = src[(long)(r0 + row) * 4096 + k0 + tx];
    }
    __syncthreads();
#pragma unroll
    for (int i = 0; i < 16; ++i) {
        int krow = (i << 2) + tq;
        dst[(long)(k0 + krow) * 4096 + r0 + tx] = f2bf(tile[tx][krow]);
    }
}

// =====================================================================
// 256x256-tile NT GEMM, 4 phases/iter, COUNTED lgkmcnt pipeline.
// C[M][N] = A[M][K] * B[N][K]^T (+bias). bf16 in, fp32 acc.
// 512 thr = 8 waves (2M x 4N), wave tile 128x64, BK=64 (K=128/iter).
// LDS: 4 regions of 16 KB (A) + 16 KB (B): region r = (buf r>>1, kh r&1)
// — same [256][32] chunk layout + XOR slot^=(row>>1)&3 both-sides
// swizzle as rounds 3-8 (0 measured conflicts).
//
// Diagnosis (r6-r9): per-wave program order [reads p -> lgkm0 -> MFMA p
// -> reads p+1] serializes the LDS pipe (~600cy/phase) with the MFMA
// pipe (~515cy/phase): 9920 cyc/iter vs ~5100 floor. Fix (T4 applied
// to lgkm): ds_reads are inline-asm into DOUBLE register banks; phase
// p issues reads for p+1, then waits lgkmcnt(12) — only p's reads —
// so p+1's reads drain UNDER p's MFMAs. sched_barrier(0) after the
// counted wait per rule 18 (stops MFMA hoisting above the wait).
//
// Per phase t: { stage region (t-1)&3 @ k=32(t+3) [4x GLD16] ;
//   12x asm ds_read region (t+1)&3 -> bank (t+1)&1 ;
//   lgkmcnt(12)+SGB ; 32 MFMA on bank t&1 ; vmcnt(4) ; s_barrier }.
// Hazard ring (verified): RAW: stage(t) confirmed by vmcnt(4) at end
// t+1 (leaves only t+1's 4 loads), read at t+2. WAR: region (t-1)&3's
// reads block-wide complete at the end-of-(t-1) barrier; stage issues
// at t. Prologue: stage r0/r1/r2, vmcnt(4) (confirms r0,r1), barrier,
// read r0->bank0; r2 confirmed by t=0's vmcnt(4). Tail: wrapped dead
// stages keep the count ring uniform.
// =====================================================================
#define MM(a, b, c) __builtin_amdgcn_mfma_f32_16x16x32_bf16(a, b, c, 0, 0, 0)

#define ARG(r) (As + (r) * 8192)
#define BRG(r) (Bs + (r) * 8192)

#define STAGE_A(r, koff) do { \
    const unsigned short* _s = A + gAr + (koff); \
    unsigned short* _d = ARG(r) + wave * 512; \
    GLD16(_s, _d); GLD16(_s + (long)128 * K, _d + 4096); } while (0)

#define STAGE_B(r, koff) do { \
    const unsigned short* _s = B + gBr + (koff); \
    unsigned short* _d = BRG(r) + wave * 512; \
    GLD16(_s, _d); GLD16(_s + (long)128 * K, _d + 4096); } while (0)

// inline-asm ds_read_b128 with compile-time byte offset
#define DSR(dst, base, imm) \
    asm volatile("ds_read_b128 %0, %1 offset:%c2" \
                 : "=v"(dst) : "v"(base), "i"(imm) : "memory")

// 12 reads: region R (literal) -> bank bk (literal). A: mh in {0,1},
// mf in {0..3} (byte off mh*4096+mf*1024); B: nf in {0..3} (nf*1024).
#define READ_AB(bk, R) do { \
    DSR(aB[bk][0][0], aByte, (R)*16384 + 0);            \
    DSR(aB[bk][0][1], aByte, (R)*16384 + 1024);         \
    DSR(aB[bk][0][2], aByte, (R)*16384 + 2048);         \
    DSR(aB[bk][0][3], aByte, (R)*16384 + 3072);         \
    DSR(aB[bk][1][0], aByte, (R)*16384 + 4096);         \
    DSR(aB[bk][1][1], aByte, (R)*16384 + 5120);         \
    DSR(aB[bk][1][2], aByte, (R)*16384 + 6144);         \
    DSR(aB[bk][1][3], aByte, (R)*16384 + 7168);         \
    DSR(bB[bk][0],    bByte, (R)*16384 + 0);            \
    DSR(bB[bk][1],    bByte, (R)*16384 + 1024);         \
    DSR(bB[bk][2],    bByte, (R)*16384 + 2048);         \
    DSR(bB[bk][3],    bByte, (R)*16384 + 3072); } while (0)

#define MFMA32(bk) do { \
    __builtin_amdgcn_s_setprio(1); \
    _Pragma("unroll") \
    for (int _h = 0; _h < 2; ++_h) \
    _Pragma("unroll") \
    for (int _m = 0; _m < 4; ++_m) { \
        acc[_h*4+_m][0] = MM(aB[bk][_h][_m], bB[bk][0], acc[_h*4+_m][0]); \
        acc[_h*4+_m][1] = MM(aB[bk][_h][_m], bB[bk][1], acc[_h*4+_m][1]); \
        acc[_h*4+_m][2] = MM(aB[bk][_h][_m], bB[bk][2], acc[_h*4+_m][2]); \
        acc[_h*4+_m][3] = MM(aB[bk][_h][_m], bB[bk][3], acc[_h*4+_m][3]); \
    } \
    __builtin_amdgcn_s_setprio(0); } while (0)

// Phase: rN = region to read (for next phase), sb = bank to fill,
// rS = region to stage, sk = its k offset, cb = bank to compute.
#define PHASE(rN, sb, rS, sk, cb) do { \
    STAGE_A(rS, sk); STAGE_B(rS, sk); \
    READ_AB(sb, rN); \
    asm volatile("s_waitcnt lgkmcnt(12)" ::: "memory"); \
    __builtin_amdgcn_sched_barrier(0); \
    MFMA32(cb); \
    asm volatile("s_waitcnt vmcnt(4)" ::: "memory"); \
    __builtin_amdgcn_s_barrier(); } while (0)

template<int OUT_BF16, int BIAS>
__global__ __launch_bounds__(512, 2) void gemm256_kernel(
    const unsigned short* __restrict__ A,   // [M][K] bf16 bits
    const unsigned short* __restrict__ B,   // [N][K] bf16 bits
    void* __restrict__ Cv, const float* __restrict__ bias,
    int M, int N, int K) {
    __shared__ unsigned short As[4 * 8192];   // 64 KB
    __shared__ unsigned short Bs[4 * 8192];   // 64 KB

    const int tid  = threadIdx.x;
    const int wave = tid >> 6;
    const int lane = tid & 63;
    const int fr   = lane & 15;
    const int fq   = lane >> 4;

    // XCD-aware bijective swizzle (nwg % 8 == 0 for all launches)
    const int nwg = gridDim.x;
    const int bid = blockIdx.x;
    const int cpx = nwg >> 3;
    const int wg  = (bid & 7) * cpx + (bid >> 3);
    const int ntn = N >> 8;
    const long m0 = (long)(wg / ntn) << 8;
    const long n0 = (long)(wg % ntn) << 8;

    const int wwr = wave >> 2;   // 0..1  (M half)
    const int wwc = wave & 3;    // 0..3  (N quarter)

    // Stage addressing (verified): region chunk [256 rows][32 k] bf16,
    // 1024 16B slots; global src slot = (si&3) ^ ((row>>1)&3).
    const int  rS  = tid >> 2;                        // rows rS and rS+128
    const int  sS  = (tid & 3) ^ ((rS >> 1) & 3);
    const long gAr = (m0 + rS) * K + sS * 8;
    const long gBr = (n0 + rS) * K + sS * 8;

    // ds_read (swizzled): elem = row*32 + ((fq ^ ((row>>1)&3))*8)
    const int swz   = (fq ^ ((fr >> 1) & 3)) * 8;
    const int aBase = (wwr * 128 + fr) * 32 + swz;
    const int bBase = (wwc * 64 + fr) * 32 + swz;
    const unsigned aByte = (unsigned)(uintptr_t)(As + aBase);
    const unsigned bByte = (unsigned)(uintptr_t)(Bs + bBase);

    f32x4  acc[8][4] = {};
    short8v aB[2][2][4], bB[2][4];

    // Prologue: stage r0@k0, r1@k32, r2@k64 (12 loads); vmcnt(4)
    // confirms r0,r1 (r2 confirmed at t=0's vmcnt(4)); read r0->bank0.
    STAGE_A(0, 0);  STAGE_B(0, 0);
    STAGE_A(1, 32); STAGE_B(1, 32);
    STAGE_A(2, 64); STAGE_B(2, 64);
    asm volatile("s_waitcnt vmcnt(4)" ::: "memory");
    __builtin_amdgcn_s_barrier();
    READ_AB(0, 0);

    const int nIter = K >> 7;   // 4 phases x K=32 per iteration
    for (int i = 0; i < nIter; ++i) {
        const int kA = 128 * i + 96;                    // in-bounds
        int k0n = 128 * i + 128; if (k0n >= K) k0n -= K; // wrap: dead
        int k1n = 128 * i + 160; if (k1n >= K) k1n -= K;
        int k2n = 128 * i + 192; if (k2n >= K) k2n -= K;

        PHASE(1, 1, 3, kA,  0);   // t0: read r1->b1, stage r3, mfma b0
        PHASE(2, 0, 0, k0n, 1);   // t1: read r2->b0, stage r0, mfma b1
        PHASE(3, 1, 1, k1n, 0);   // t2: read r3->b1, stage r1, mfma b0
        PHASE(0, 0, 2, k2n, 1);   // t3: read r0->b0, stage r2, mfma b1
    }

    // Epilogue: C/D layout col = lane&15, row = (lane>>4)*4 + j
#pragma unroll
    for (int nf = 0; nf < 4; ++nf) {
        const int col = (int)n0 + wwc * 64 + nf * 16 + fr;
        float bv = BIAS ? bias[col] : 0.0f;
#pragma unroll
        for (int mf = 0; mf < 8; ++mf) {
            f32x4 v = acc[mf][nf];
            long rowb = m0 + wwr * 128 + mf * 16 + fq * 4;
#pragma unroll
            for (int j = 0; j < 4; ++j) {
                float val = v[j] + bv;
                long off = (rowb + j) * N + col;
                if (OUT_BF16) ((unsigned short*)Cv)[off] = f2bf(val);
                else          ((float*)Cv)[off] = val;
            }
        }
    }
}

extern "C" void kernel_launch(void* const* d_in, const int* in_sizes, int n_in,
                              void* d_out, int out_size, void* d_ws, size_t ws_size,
                              hipStream_t stream) {
    const float* x    = (const float*)d_in[0];   // [4,2048,4096] = [8192][4096]
    const float* U    = (const float*)d_in[1];   // [4096][4096]
    const float* S    = (const float*)d_in[2];   // [4096]
    const float* Vt   = (const float*)d_in[3];   // [4096][4096]
    const float* eps  = (const float*)d_in[4];   // [4096]
    const float* bias = (const float*)d_in[5];   // [4096]
    float* out = (float*)d_out;                  // [8192][4096] fp32

    char* ws = (char*)d_ws;
    unsigned short* Ub  = (unsigned short*)(ws);                       // 32 MB
    unsigned short* VtT = (unsigned short*)(ws + (size_t)(32 << 20));  // 32 MB
    unsigned short* Wb  = (unsigned short*)(ws + (size_t)(64 << 20));  // 32 MB
    unsigned short* Xb  = (unsigned short*)(ws);  // 64 MB, reuses Ub+VtT after GEMM1

    // 1) Ub = bf16(U * (S+eps))            [o][r]
    prep_u_kernel<<<8192, 256, 0, stream>>>(U, S, eps, Ub);
    // 2) VtT = bf16(Vt^T)                  [k][r]
    transpose_cvt_kernel<<<dim3(64, 64), 256, 0, stream>>>(Vt, VtT);
    // 3) Wb[o][k] = Ub @ VtT^T             (NT, K=r)  -> 256 wg
    gemm256_kernel<1, 0><<<256, 512, 0, stream>>>(Ub, VtT, (void*)Wb, nullptr,
                                                  4096, 4096, 4096);
    // 4) Xb = bf16(x)                      [m][k]  (overwrites Ub/VtT — now dead)
    cvt_bf16_kernel<<<16384, 256, 0, stream>>>(x, Xb);
    // 5) out[m][o] = Xb @ Wb^T + bias      (NT, K=k)  -> 512 wg
    gemm256_kernel<0, 1><<<512, 512, 0, stream>>>(Xb, Wb, (void*)out, bias,
                                                  8192, 4096, 4096);
}

// Round 11
// 434.204 us; speedup vs baseline: 1.1779x; 1.0182x over previous
//
#include <hip/hip_runtime.h>
#include <hip/hip_bf16.h>
#include <stdint.h>

typedef __attribute__((ext_vector_type(4))) float f32x4;
typedef __attribute__((ext_vector_type(8))) short short8v;

typedef __attribute__((address_space(1))) void gvoid;
typedef __attribute__((address_space(3))) void lvoid;

#define GLD16(gp, lp) __builtin_amdgcn_global_load_lds((const gvoid*)(gp), (lvoid*)(lp), 16, 0, 0)

__device__ __forceinline__ unsigned short f2bf(float f) {
    union { float ff; unsigned uu; } a; a.ff = f;
    unsigned u = a.uu;
    u += 0x7FFFu + ((u >> 16) & 1u);   // RNE; inputs finite
    return (unsigned short)(u >> 16);
}

// ---- Ub[o][r] = bf16(U[o][r] * (S[r]+eps[r])), row-major [4096][4096] ----
__global__ __launch_bounds__(256) void prep_u_kernel(
    const float* __restrict__ U, const float* __restrict__ S,
    const float* __restrict__ eps, unsigned short* __restrict__ Ub) {
    long idx = ((long)blockIdx.x * 256 + threadIdx.x) * 8;
    int r = (int)(idx & 4095);
    f32x4 u0 = *(const f32x4*)(U + idx);
    f32x4 u1 = *(const f32x4*)(U + idx + 4);
    f32x4 s0 = *(const f32x4*)(S + r);
    f32x4 s1 = *(const f32x4*)(S + r + 4);
    f32x4 e0 = *(const f32x4*)(eps + r);
    f32x4 e1 = *(const f32x4*)(eps + r + 4);
    union { uint4 v; unsigned short s[8]; } o;
#pragma unroll
    for (int j = 0; j < 4; ++j) {
        o.s[j]     = f2bf(u0[j] * (s0[j] + e0[j]));
        o.s[j + 4] = f2bf(u1[j] * (s1[j] + e1[j]));
    }
    *(uint4*)(Ub + idx) = o.v;
}

// ---- generic fp32 -> bf16 convert, 8 elems/thread ----
__global__ __launch_bounds__(256) void cvt_bf16_kernel(
    const float* __restrict__ src, unsigned short* __restrict__ dst) {
    long idx = ((long)blockIdx.x * 256 + threadIdx.x) * 8;
    f32x4 v0 = *(const f32x4*)(src + idx);
    f32x4 v1 = *(const f32x4*)(src + idx + 4);
    union { uint4 v; unsigned short s[8]; } o;
#pragma unroll
    for (int j = 0; j < 4; ++j) {
        o.s[j]     = f2bf(v0[j]);
        o.s[j + 4] = f2bf(v1[j]);
    }
    *(uint4*)(dst + idx) = o.v;
}

// ---- VtT[k][r] = bf16(Vt[r][k]); 64x64 tiles, padded LDS (conflict-free) ----
__global__ __launch_bounds__(256) void transpose_cvt_kernel(
    const float* __restrict__ src, unsigned short* __restrict__ dst) {
    __shared__ float tile[64][65];
    int tx = threadIdx.x & 63;
    int tq = threadIdx.x >> 6;
    int r0 = blockIdx.y << 6;
    int k0 = blockIdx.x << 6;
#pragma unroll
    for (int i = 0; i < 16; ++i) {
        int row = (i << 2) + tq;
        tile[row][tx] = src[(long)(r0 + row) * 4096 + k0 + tx];
    }
    __syncthreads();
#pragma unroll
    for (int i = 0; i < 16; ++i) {
        int krow = (i << 2) + tq;
        dst[(long)(k0 + krow) * 4096 + r0 + tx] = f2bf(tile[tx][krow]);
    }
}

// =====================================================================
// 256x256-tile NT GEMM, 4 phases/iter, counted-lgkm pipeline (r10) +
// T19 sched_group_barrier interleave {MFMA x2, DS_READ x1}.
// C[M][N] = A[M][K] * B[N][K]^T (+bias). bf16 in, fp32 acc.
// 512 thr = 8 waves (2M x 4N), wave tile 128x64, BK=64 (K=128/iter).
// LDS: 4 regions x (16KB A + 16KB B), [256][32] chunks, XOR swizzle
// slot^=(row>>1)&3 both-sides (0 conflicts since r3).
//
// r10 result: counted lgkm pipeline 264->244us, MfmaUtil 51%. Phase =
// 2290cy vs ~1300 model (MFMA 1024 + LDS drain 1150 overlapped) —
// reads still bunch at phase start, MFMAs at phase end (in-order wave
// issue). Fix: emit lgkmcnt(0) BEFORE reads (drains only last phase's
// 12, ~free), sched_barrier(0) wall (rule 18), then 12 asm ds_reads +
// 32 MFMAs with sched_group_barrier pattern {MFMA,2}{DS_READ,1} x12 +
// {MFMA,8} — reads issue in MFMA pipe-backpressure gaps and drain
// under THIS phase's burst (AITER/CK-v3 pattern; T19's proper home).
// DSR: volatile (ordered vs barriers/waits) WITHOUT "memory" so MFMAs
// can interleave (rule-18 precedent: MFMA crosses asm-with-memory).
// Ring/hazards identical to r10 (verified): RAW stage t -> vmcnt(4)
// end t+1 -> read t+2; WAR reads of region done block-wide at end-of-
// phase barrier before re-stage.
// =====================================================================
#define MM(a, b, c) __builtin_amdgcn_mfma_f32_16x16x32_bf16(a, b, c, 0, 0, 0)

#define ARG(r) (As + (r) * 8192)
#define BRG(r) (Bs + (r) * 8192)

#define STAGE_A(r, koff) do { \
    const unsigned short* _s = A + gAr + (koff); \
    unsigned short* _d = ARG(r) + wave * 512; \
    GLD16(_s, _d); GLD16(_s + (long)128 * K, _d + 4096); } while (0)

#define STAGE_B(r, koff) do { \
    const unsigned short* _s = B + gBr + (koff); \
    unsigned short* _d = BRG(r) + wave * 512; \
    GLD16(_s, _d); GLD16(_s + (long)128 * K, _d + 4096); } while (0)

// inline-asm ds_read_b128, volatile (ordered vs volatile waits/barriers)
// but NO "memory" clobber -> scheduler may interleave MFMAs between.
#define DSR(dst, base, imm) \
    asm volatile("ds_read_b128 %0, %1 offset:%c2" \
                 : "=v"(dst) : "v"(base), "i"(imm))

// 12 reads: region R (literal) -> bank bk (literal).
#define READ_AB(bk, R) do { \
    DSR(aB[bk][0][0], aByte, (R)*16384 + 0);            \
    DSR(aB[bk][0][1], aByte, (R)*16384 + 1024);         \
    DSR(aB[bk][0][2], aByte, (R)*16384 + 2048);         \
    DSR(aB[bk][0][3], aByte, (R)*16384 + 3072);         \
    DSR(aB[bk][1][0], aByte, (R)*16384 + 4096);         \
    DSR(aB[bk][1][1], aByte, (R)*16384 + 5120);         \
    DSR(aB[bk][1][2], aByte, (R)*16384 + 6144);         \
    DSR(aB[bk][1][3], aByte, (R)*16384 + 7168);         \
    DSR(bB[bk][0],    bByte, (R)*16384 + 0);            \
    DSR(bB[bk][1],    bByte, (R)*16384 + 1024);         \
    DSR(bB[bk][2],    bByte, (R)*16384 + 2048);         \
    DSR(bB[bk][3],    bByte, (R)*16384 + 3072); } while (0)

#define MFMA32(bk) do { \
    _Pragma("unroll") \
    for (int _h = 0; _h < 2; ++_h) \
    _Pragma("unroll") \
    for (int _m = 0; _m < 4; ++_m) { \
        acc[_h*4+_m][0] = MM(aB[bk][_h][_m], bB[bk][0], acc[_h*4+_m][0]); \
        acc[_h*4+_m][1] = MM(aB[bk][_h][_m], bB[bk][1], acc[_h*4+_m][1]); \
        acc[_h*4+_m][2] = MM(aB[bk][_h][_m], bB[bk][2], acc[_h*4+_m][2]); \
        acc[_h*4+_m][3] = MM(aB[bk][_h][_m], bB[bk][3], acc[_h*4+_m][3]); \
    } } while (0)

#define SGB __builtin_amdgcn_sched_group_barrier

// Phase: rN = region to read (consumed next phase), sb = bank to fill,
// rS = region to stage, sk = its k offset, cb = bank to compute.
#define PHASE(rN, sb, rS, sk, cb) do { \
    STAGE_A(rS, sk); STAGE_B(rS, sk); \
    asm volatile("s_waitcnt lgkmcnt(0)" ::: "memory"); \
    __builtin_amdgcn_sched_barrier(0); \
    __builtin_amdgcn_s_setprio(1); \
    READ_AB(sb, rN); \
    MFMA32(cb); \
    _Pragma("unroll") \
    for (int _g = 0; _g < 12; ++_g) { SGB(0x008, 2, 0); SGB(0x100, 1, 0); } \
    SGB(0x008, 8, 0); \
    __builtin_amdgcn_s_setprio(0); \
    asm volatile("s_waitcnt vmcnt(4)" ::: "memory"); \
    __builtin_amdgcn_s_barrier(); } while (0)

template<int OUT_BF16, int BIAS>
__global__ __launch_bounds__(512, 2) void gemm256_kernel(
    const unsigned short* __restrict__ A,   // [M][K] bf16 bits
    const unsigned short* __restrict__ B,   // [N][K] bf16 bits
    void* __restrict__ Cv, const float* __restrict__ bias,
    int M, int N, int K) {
    __shared__ unsigned short As[4 * 8192];   // 64 KB
    __shared__ unsigned short Bs[4 * 8192];   // 64 KB

    const int tid  = threadIdx.x;
    const int wave = tid >> 6;
    const int lane = tid & 63;
    const int fr   = lane & 15;
    const int fq   = lane >> 4;

    // XCD-aware bijective swizzle (nwg % 8 == 0 for all launches)
    const int nwg = gridDim.x;
    const int bid = blockIdx.x;
    const int cpx = nwg >> 3;
    const int wg  = (bid & 7) * cpx + (bid >> 3);
    const int ntn = N >> 8;
    const long m0 = (long)(wg / ntn) << 8;
    const long n0 = (long)(wg % ntn) << 8;

    const int wwr = wave >> 2;   // 0..1  (M half)
    const int wwc = wave & 3;    // 0..3  (N quarter)

    // Stage addressing (verified): region chunk [256 rows][32 k] bf16,
    // 1024 16B slots; global src slot = (si&3) ^ ((row>>1)&3).
    const int  rS  = tid >> 2;                        // rows rS and rS+128
    const int  sS  = (tid & 3) ^ ((rS >> 1) & 3);
    const long gAr = (m0 + rS) * K + sS * 8;
    const long gBr = (n0 + rS) * K + sS * 8;

    // ds_read (swizzled): elem = row*32 + ((fq ^ ((row>>1)&3))*8)
    const int swz   = (fq ^ ((fr >> 1) & 3)) * 8;
    const int aBase = (wwr * 128 + fr) * 32 + swz;
    const int bBase = (wwc * 64 + fr) * 32 + swz;
    const unsigned aByte = (unsigned)(uintptr_t)(As + aBase);
    const unsigned bByte = (unsigned)(uintptr_t)(Bs + bBase);

    f32x4  acc[8][4] = {};
    short8v aB[2][2][4], bB[2][4];

    // Prologue: stage r0@k0, r1@k32, r2@k64; vmcnt(4) confirms r0,r1
    // (r2 confirmed by t=0's vmcnt(4)); read r0 -> bank0.
    STAGE_A(0, 0);  STAGE_B(0, 0);
    STAGE_A(1, 32); STAGE_B(1, 32);
    STAGE_A(2, 64); STAGE_B(2, 64);
    asm volatile("s_waitcnt vmcnt(4)" ::: "memory");
    __builtin_amdgcn_s_barrier();
    READ_AB(0, 0);

    const int nIter = K >> 7;   // 4 phases x K=32 per iteration
    for (int i = 0; i < nIter; ++i) {
        const int kA = 128 * i + 96;                    // in-bounds
        int k0n = 128 * i + 128; if (k0n >= K) k0n -= K; // wrap: dead
        int k1n = 128 * i + 160; if (k1n >= K) k1n -= K;
        int k2n = 128 * i + 192; if (k2n >= K) k2n -= K;

        PHASE(1, 1, 3, kA,  0);   // t0: read r1->b1, stage r3, mfma b0
        PHASE(2, 0, 0, k0n, 1);   // t1: read r2->b0, stage r0, mfma b1
        PHASE(3, 1, 1, k1n, 0);   // t2: read r3->b1, stage r1, mfma b0
        PHASE(0, 0, 2, k2n, 1);   // t3: read r0->b0, stage r2, mfma b1
    }

    // Epilogue: C/D layout col = lane&15, row = (lane>>4)*4 + j
#pragma unroll
    for (int nf = 0; nf < 4; ++nf) {
        const int col = (int)n0 + wwc * 64 + nf * 16 + fr;
        float bv = BIAS ? bias[col] : 0.0f;
#pragma unroll
        for (int mf = 0; mf < 8; ++mf) {
            f32x4 v = acc[mf][nf];
            long rowb = m0 + wwr * 128 + mf * 16 + fq * 4;
#pragma unroll
            for (int j = 0; j < 4; ++j) {
                float val = v[j] + bv;
                long off = (rowb + j) * N + col;
                if (OUT_BF16) ((unsigned short*)Cv)[off] = f2bf(val);
                else          ((float*)Cv)[off] = val;
            }
        }
    }
}

extern "C" void kernel_launch(void* const* d_in, const int* in_sizes, int n_in,
                              void* d_out, int out_size, void* d_ws, size_t ws_size,
                              hipStream_t stream) {
    const float* x    = (const float*)d_in[0];   // [4,2048,4096] = [8192][4096]
    const float* U    = (const float*)d_in[1];   // [4096][4096]
    const float* S    = (const float*)d_in[2];   // [4096]
    const float* Vt   = (const float*)d_in[3];   // [4096][4096]
    const float* eps  = (const float*)d_in[4];   // [4096]
    const float* bias = (const float*)d_in[5];   // [4096]
    float* out = (float*)d_out;                  // [8192][4096] fp32

    char* ws = (char*)d_ws;
    unsigned short* Ub  = (unsigned short*)(ws);                       // 32 MB
    unsigned short* VtT = (unsigned short*)(ws + (size_t)(32 << 20));  // 32 MB
    unsigned short* Wb  = (unsigned short*)(ws + (size_t)(64 << 20));  // 32 MB
    unsigned short* Xb  = (unsigned short*)(ws);  // 64 MB, reuses Ub+VtT after GEMM1

    // 1) Ub = bf16(U * (S+eps))            [o][r]
    prep_u_kernel<<<8192, 256, 0, stream>>>(U, S, eps, Ub);
    // 2) VtT = bf16(Vt^T)                  [k][r]
    transpose_cvt_kernel<<<dim3(64, 64), 256, 0, stream>>>(Vt, VtT);
    // 3) Wb[o][k] = Ub @ VtT^T             (NT, K=r)  -> 256 wg
    gemm256_kernel<1, 0><<<256, 512, 0, stream>>>(Ub, VtT, (void*)Wb, nullptr,
                                                  4096, 4096, 4096);
    // 4) Xb = bf16(x)                      [m][k]  (overwrites Ub/VtT — now dead)
    cvt_bf16_kernel<<<16384, 256, 0, stream>>>(x, Xb);
    // 5) out[m][o] = Xb @ Wb^T + bias      (NT, K=k)  -> 512 wg
    gemm256_kernel<0, 1><<<512, 512, 0, stream>>>(Xb, Wb, (void*)out, bias,
                                                  8192, 4096, 4096);
}

// Round 12
// 433.575 us; speedup vs baseline: 1.1797x; 1.0015x over previous
//
#include <hip/hip_runtime.h>
#include <hip/hip_bf16.h>
#include <stdint.h>

typedef __attribute__((ext_vector_type(4))) float f32x4;
typedef __attribute__((ext_vector_type(8))) short short8v;

typedef __attribute__((address_space(1))) void gvoid;
typedef __attribute__((address_space(3))) void lvoid;

#define GLD16(gp, lp) __builtin_amdgcn_global_load_lds((const gvoid*)(gp), (lvoid*)(lp), 16, 0, 0)

__device__ __forceinline__ unsigned short f2bf(float f) {
    union { float ff; unsigned uu; } a; a.ff = f;
    unsigned u = a.uu;
    u += 0x7FFFu + ((u >> 16) & 1u);   // RNE; inputs finite
    return (unsigned short)(u >> 16);
}

// ---- fused: Ub[o][r] = bf16(U[o][r]*(S[r]+eps[r]))  (blocks 0..8191)
//             VtT[k][r] = bf16(Vt[r][k])              (blocks 8192..12287)
__global__ __launch_bounds__(256) void prep_fused_kernel(
    const float* __restrict__ U, const float* __restrict__ S,
    const float* __restrict__ eps, unsigned short* __restrict__ Ub,
    const float* __restrict__ Vt, unsigned short* __restrict__ VtT) {
    __shared__ float tile[64][65];
    if (blockIdx.x < 8192) {
        long idx = ((long)blockIdx.x * 256 + threadIdx.x) * 8;
        int r = (int)(idx & 4095);
        f32x4 u0 = *(const f32x4*)(U + idx);
        f32x4 u1 = *(const f32x4*)(U + idx + 4);
        f32x4 s0 = *(const f32x4*)(S + r);
        f32x4 s1 = *(const f32x4*)(S + r + 4);
        f32x4 e0 = *(const f32x4*)(eps + r);
        f32x4 e1 = *(const f32x4*)(eps + r + 4);
        union { uint4 v; unsigned short s[8]; } o;
#pragma unroll
        for (int j = 0; j < 4; ++j) {
            o.s[j]     = f2bf(u0[j] * (s0[j] + e0[j]));
            o.s[j + 4] = f2bf(u1[j] * (s1[j] + e1[j]));
        }
        *(uint4*)(Ub + idx) = o.v;
    } else {
        int t  = blockIdx.x - 8192;
        int k0 = (t & 63) << 6;
        int r0 = (t >> 6) << 6;
        int tx = threadIdx.x & 63;
        int tq = threadIdx.x >> 6;
#pragma unroll
        for (int i = 0; i < 16; ++i) {
            int row = (i << 2) + tq;
            tile[row][tx] = Vt[(long)(r0 + row) * 4096 + k0 + tx];
        }
        __syncthreads();
#pragma unroll
        for (int i = 0; i < 16; ++i) {
            int krow = (i << 2) + tq;
            VtT[(long)(k0 + krow) * 4096 + r0 + tx] = f2bf(tile[tx][krow]);
        }
    }
}

// ---- generic fp32 -> bf16 convert, 8 elems/thread ----
__global__ __launch_bounds__(256) void cvt_bf16_kernel(
    const float* __restrict__ src, unsigned short* __restrict__ dst) {
    long idx = ((long)blockIdx.x * 256 + threadIdx.x) * 8;
    f32x4 v0 = *(const f32x4*)(src + idx);
    f32x4 v1 = *(const f32x4*)(src + idx + 4);
    union { uint4 v; unsigned short s[8]; } o;
#pragma unroll
    for (int j = 0; j < 4; ++j) {
        o.s[j]     = f2bf(v0[j]);
        o.s[j + 4] = f2bf(v1[j]);
    }
    *(uint4*)(dst + idx) = o.v;
}

// =====================================================================
// 256x256-tile NT GEMM, 4 phases/iter, counted-lgkm pipeline + T19 SGB
// (r11 structure, unchanged) + NEW: n-pair XCD clustering.
//
// Supply analysis (r3-r11): staged bytes/cycle constant at 13-15 B/cyc
// /CU across ALL sync structures -> operand-supply-bound, dominated by
// the L3-resident B-panel stream (per-XCD B working set was 32 MB).
// Fix: map each XCD's wgs to 2 n-columns x all m (was 4 m-rows x all
// n): B working set/XCD = 4 MB -> L2-resident; paired blocks reading
// the same A-panel sit on the SAME XCD (2nd read = L2 hit). L3 traffic
// ~1.06 GB -> ~0.55 GB for GEMM2.
//   n_idx = 2*(wg/cpx) + (wg&1), m_idx = (wg>>1) & (M/256-1)
// (bijective for ntn=16, verified; same tiles, same math.)
// =====================================================================
#define MM(a, b, c) __builtin_amdgcn_mfma_f32_16x16x32_bf16(a, b, c, 0, 0, 0)

#define ARG(r) (As + (r) * 8192)
#define BRG(r) (Bs + (r) * 8192)

#define STAGE_A(r, koff) do { \
    const unsigned short* _s = A + gAr + (koff); \
    unsigned short* _d = ARG(r) + wave * 512; \
    GLD16(_s, _d); GLD16(_s + (long)128 * K, _d + 4096); } while (0)

#define STAGE_B(r, koff) do { \
    const unsigned short* _s = B + gBr + (koff); \
    unsigned short* _d = BRG(r) + wave * 512; \
    GLD16(_s, _d); GLD16(_s + (long)128 * K, _d + 4096); } while (0)

// inline-asm ds_read_b128, volatile, no "memory" clobber (r11)
#define DSR(dst, base, imm) \
    asm volatile("ds_read_b128 %0, %1 offset:%c2" \
                 : "=v"(dst) : "v"(base), "i"(imm))

#define READ_AB(bk, R) do { \
    DSR(aB[bk][0][0], aByte, (R)*16384 + 0);            \
    DSR(aB[bk][0][1], aByte, (R)*16384 + 1024);         \
    DSR(aB[bk][0][2], aByte, (R)*16384 + 2048);         \
    DSR(aB[bk][0][3], aByte, (R)*16384 + 3072);         \
    DSR(aB[bk][1][0], aByte, (R)*16384 + 4096);         \
    DSR(aB[bk][1][1], aByte, (R)*16384 + 5120);         \
    DSR(aB[bk][1][2], aByte, (R)*16384 + 6144);         \
    DSR(aB[bk][1][3], aByte, (R)*16384 + 7168);         \
    DSR(bB[bk][0],    bByte, (R)*16384 + 0);            \
    DSR(bB[bk][1],    bByte, (R)*16384 + 1024);         \
    DSR(bB[bk][2],    bByte, (R)*16384 + 2048);         \
    DSR(bB[bk][3],    bByte, (R)*16384 + 3072); } while (0)

#define MFMA32(bk) do { \
    _Pragma("unroll") \
    for (int _h = 0; _h < 2; ++_h) \
    _Pragma("unroll") \
    for (int _m = 0; _m < 4; ++_m) { \
        acc[_h*4+_m][0] = MM(aB[bk][_h][_m], bB[bk][0], acc[_h*4+_m][0]); \
        acc[_h*4+_m][1] = MM(aB[bk][_h][_m], bB[bk][1], acc[_h*4+_m][1]); \
        acc[_h*4+_m][2] = MM(aB[bk][_h][_m], bB[bk][2], acc[_h*4+_m][2]); \
        acc[_h*4+_m][3] = MM(aB[bk][_h][_m], bB[bk][3], acc[_h*4+_m][3]); \
    } } while (0)

#define SGB __builtin_amdgcn_sched_group_barrier

#define PHASE(rN, sb, rS, sk, cb) do { \
    STAGE_A(rS, sk); STAGE_B(rS, sk); \
    asm volatile("s_waitcnt lgkmcnt(0)" ::: "memory"); \
    __builtin_amdgcn_sched_barrier(0); \
    __builtin_amdgcn_s_setprio(1); \
    READ_AB(sb, rN); \
    MFMA32(cb); \
    _Pragma("unroll") \
    for (int _g = 0; _g < 12; ++_g) { SGB(0x008, 2, 0); SGB(0x100, 1, 0); } \
    SGB(0x008, 8, 0); \
    __builtin_amdgcn_s_setprio(0); \
    asm volatile("s_waitcnt vmcnt(4)" ::: "memory"); \
    __builtin_amdgcn_s_barrier(); } while (0)

template<int OUT_BF16, int BIAS>
__global__ __launch_bounds__(512, 2) void gemm256_kernel(
    const unsigned short* __restrict__ A,   // [M][K] bf16 bits
    const unsigned short* __restrict__ B,   // [N][K] bf16 bits
    void* __restrict__ Cv, const float* __restrict__ bias,
    int M, int N, int K) {
    __shared__ unsigned short As[4 * 8192];   // 64 KB
    __shared__ unsigned short Bs[4 * 8192];   // 64 KB

    const int tid  = threadIdx.x;
    const int wave = tid >> 6;
    const int lane = tid & 63;
    const int fr   = lane & 15;
    const int fq   = lane >> 4;

    // XCD-aware bijective swizzle + n-pair clustering (ntn == 16).
    // XCD x <- wgs [x*cpx, (x+1)*cpx): n = 2x + (wg&1)  (B: 4 MB, L2-fit)
    //                                  m = (wg>>1) & (nmt-1)
    const int nwg = gridDim.x;
    const int bid = blockIdx.x;
    const int cpx = nwg >> 3;
    const int wg  = (bid & 7) * cpx + (bid >> 3);
    const int nmt = M >> 8;
    const long n0 = (long)(2 * (wg / cpx) + (wg & 1)) << 8;
    const long m0 = (long)((wg >> 1) & (nmt - 1)) << 8;

    const int wwr = wave >> 2;   // 0..1  (M half)
    const int wwc = wave & 3;    // 0..3  (N quarter)

    // Stage addressing (verified): region chunk [256 rows][32 k] bf16,
    // 1024 16B slots; global src slot = (si&3) ^ ((row>>1)&3).
    const int  rS  = tid >> 2;                        // rows rS and rS+128
    const int  sS  = (tid & 3) ^ ((rS >> 1) & 3);
    const long gAr = (m0 + rS) * K + sS * 8;
    const long gBr = (n0 + rS) * K + sS * 8;

    // ds_read (swizzled): elem = row*32 + ((fq ^ ((row>>1)&3))*8)
    const int swz   = (fq ^ ((fr >> 1) & 3)) * 8;
    const int aBase = (wwr * 128 + fr) * 32 + swz;
    const int bBase = (wwc * 64 + fr) * 32 + swz;
    const unsigned aByte = (unsigned)(uintptr_t)(As + aBase);
    const unsigned bByte = (unsigned)(uintptr_t)(Bs + bBase);

    f32x4  acc[8][4] = {};
    short8v aB[2][2][4], bB[2][4];

    // Prologue: stage r0@k0, r1@k32, r2@k64; vmcnt(4) confirms r0,r1
    // (r2 confirmed by t=0's vmcnt(4)); read r0 -> bank0.
    STAGE_A(0, 0);  STAGE_B(0, 0);
    STAGE_A(1, 32); STAGE_B(1, 32);
    STAGE_A(2, 64); STAGE_B(2, 64);
    asm volatile("s_waitcnt vmcnt(4)" ::: "memory");
    __builtin_amdgcn_s_barrier();
    READ_AB(0, 0);

    const int nIter = K >> 7;   // 4 phases x K=32 per iteration
    for (int i = 0; i < nIter; ++i) {
        const int kA = 128 * i + 96;                    // in-bounds
        int k0n = 128 * i + 128; if (k0n >= K) k0n -= K; // wrap: dead
        int k1n = 128 * i + 160; if (k1n >= K) k1n -= K;
        int k2n = 128 * i + 192; if (k2n >= K) k2n -= K;

        PHASE(1, 1, 3, kA,  0);   // t0: read r1->b1, stage r3, mfma b0
        PHASE(2, 0, 0, k0n, 1);   // t1: read r2->b0, stage r0, mfma b1
        PHASE(3, 1, 1, k1n, 0);   // t2: read r3->b1, stage r1, mfma b0
        PHASE(0, 0, 2, k2n, 1);   // t3: read r0->b0, stage r2, mfma b1
    }

    // Epilogue: C/D layout col = lane&15, row = (lane>>4)*4 + j
#pragma unroll
    for (int nf = 0; nf < 4; ++nf) {
        const int col = (int)n0 + wwc * 64 + nf * 16 + fr;
        float bv = BIAS ? bias[col] : 0.0f;
#pragma unroll
        for (int mf = 0; mf < 8; ++mf) {
            f32x4 v = acc[mf][nf];
            long rowb = m0 + wwr * 128 + mf * 16 + fq * 4;
#pragma unroll
            for (int j = 0; j < 4; ++j) {
                float val = v[j] + bv;
                long off = (rowb + j) * N + col;
                if (OUT_BF16) ((unsigned short*)Cv)[off] = f2bf(val);
                else          ((float*)Cv)[off] = val;
            }
        }
    }
}

extern "C" void kernel_launch(void* const* d_in, const int* in_sizes, int n_in,
                              void* d_out, int out_size, void* d_ws, size_t ws_size,
                              hipStream_t stream) {
    const float* x    = (const float*)d_in[0];   // [4,2048,4096] = [8192][4096]
    const float* U    = (const float*)d_in[1];   // [4096][4096]
    const float* S    = (const float*)d_in[2];   // [4096]
    const float* Vt   = (const float*)d_in[3];   // [4096][4096]
    const float* eps  = (const float*)d_in[4];   // [4096]
    const float* bias = (const float*)d_in[5];   // [4096]
    float* out = (float*)d_out;                  // [8192][4096] fp32

    char* ws = (char*)d_ws;
    unsigned short* Ub  = (unsigned short*)(ws);                       // 32 MB
    unsigned short* VtT = (unsigned short*)(ws + (size_t)(32 << 20));  // 32 MB
    unsigned short* Wb  = (unsigned short*)(ws + (size_t)(64 << 20));  // 32 MB
    unsigned short* Xb  = (unsigned short*)(ws);  // 64 MB, reuses Ub+VtT after GEMM1

    // 1) Ub = bf16(U*(S+eps)) ; VtT = bf16(Vt^T)   (fused, independent)
    prep_fused_kernel<<<12288, 256, 0, stream>>>(U, S, eps, Ub, Vt, VtT);
    // 2) Wb[o][k] = Ub @ VtT^T             (NT, K=r)  -> 256 wg
    gemm256_kernel<1, 0><<<256, 512, 0, stream>>>(Ub, VtT, (void*)Wb, nullptr,
                                                  4096, 4096, 4096);
    // 3) Xb = bf16(x)                      [m][k]  (overwrites Ub/VtT — now dead)
    cvt_bf16_kernel<<<16384, 256, 0, stream>>>(x, Xb);
    // 4) out[m][o] = Xb @ Wb^T + bias      (NT, K=k)  -> 512 wg
    gemm256_kernel<0, 1><<<512, 512, 0, stream>>>(Xb, Wb, (void*)out, bias,
                                                  8192, 4096, 4096);
}

// Round 13
// 426.325 us; speedup vs baseline: 1.1997x; 1.0170x over previous
//
#include <hip/hip_runtime.h>
#include <hip/hip_bf16.h>
#include <stdint.h>

typedef __attribute__((ext_vector_type(4))) float f32x4;
typedef __attribute__((ext_vector_type(8))) short short8v;

typedef __attribute__((address_space(1))) void gvoid;
typedef __attribute__((address_space(3))) void lvoid;

#define GLD16(gp, lp) __builtin_amdgcn_global_load_lds((const gvoid*)(gp), (lvoid*)(lp), 16, 0, 0)

__device__ __forceinline__ unsigned short f2bf(float f) {
    union { float ff; unsigned uu; } a; a.ff = f;
    unsigned u = a.uu;
    u += 0x7FFFu + ((u >> 16) & 1u);   // RNE; inputs finite
    return (unsigned short)(u >> 16);
}

// ---- fused: Ub[o][r] = bf16(U[o][r]*(S[r]+eps[r]))  (blocks 0..8191)
//             VtT[k][r] = bf16(Vt[r][k])              (blocks 8192..12287)
__global__ __launch_bounds__(256) void prep_fused_kernel(
    const float* __restrict__ U, const float* __restrict__ S,
    const float* __restrict__ eps, unsigned short* __restrict__ Ub,
    const float* __restrict__ Vt, unsigned short* __restrict__ VtT) {
    __shared__ float tile[64][65];
    if (blockIdx.x < 8192) {
        long idx = ((long)blockIdx.x * 256 + threadIdx.x) * 8;
        int r = (int)(idx & 4095);
        f32x4 u0 = *(const f32x4*)(U + idx);
        f32x4 u1 = *(const f32x4*)(U + idx + 4);
        f32x4 s0 = *(const f32x4*)(S + r);
        f32x4 s1 = *(const f32x4*)(S + r + 4);
        f32x4 e0 = *(const f32x4*)(eps + r);
        f32x4 e1 = *(const f32x4*)(eps + r + 4);
        union { uint4 v; unsigned short s[8]; } o;
#pragma unroll
        for (int j = 0; j < 4; ++j) {
            o.s[j]     = f2bf(u0[j] * (s0[j] + e0[j]));
            o.s[j + 4] = f2bf(u1[j] * (s1[j] + e1[j]));
        }
        *(uint4*)(Ub + idx) = o.v;
    } else {
        int t  = blockIdx.x - 8192;
        int k0 = (t & 63) << 6;
        int r0 = (t >> 6) << 6;
        int tx = threadIdx.x & 63;
        int tq = threadIdx.x >> 6;
#pragma unroll
        for (int i = 0; i < 16; ++i) {
            int row = (i << 2) + tq;
            tile[row][tx] = Vt[(long)(r0 + row) * 4096 + k0 + tx];
        }
        __syncthreads();
#pragma unroll
        for (int i = 0; i < 16; ++i) {
            int krow = (i << 2) + tq;
            VtT[(long)(k0 + krow) * 4096 + r0 + tx] = f2bf(tile[tx][krow]);
        }
    }
}

// ---- generic fp32 -> bf16 convert (fallback path only) ----
__global__ __launch_bounds__(256) void cvt_bf16_kernel(
    const float* __restrict__ src, unsigned short* __restrict__ dst) {
    long idx = ((long)blockIdx.x * 256 + threadIdx.x) * 8;
    f32x4 v0 = *(const f32x4*)(src + idx);
    f32x4 v1 = *(const f32x4*)(src + idx + 4);
    union { uint4 v; unsigned short s[8]; } o;
#pragma unroll
    for (int j = 0; j < 4; ++j) {
        o.s[j]     = f2bf(v0[j]);
        o.s[j + 4] = f2bf(v1[j]);
    }
    *(uint4*)(dst + idx) = o.v;
}

// =====================================================================
// 256x256-tile NT GEMM, 4 phases/iter, counted-lgkm pipeline + T19 SGB
// (r11/r12 structure) + NEW: DO_CVT weave — GEMM1 additionally streams
// the x f32->bf16 conversion (1 chunk of 8 f32 per thread per iter, in
// P1), hiding the former 35us cvt kernel under GEMM1's idle HBM.
//
// vmcnt ring with cvt (gfx9: stores count in vmcnt, ISA doc §5/§7):
//  P1 window = st1 + ld2 + stage4 = 7  -> vmcnt(7)  (i==0: 6 -> vmcnt(6))
//  P2..P4 unchanged vmcnt(4).
//  - prev P4's stages confirmed by P1-end vmcnt(7) (drains oldest 4) OK
//  - P1's stages confirmed by P2-end vmcnt(4) (drains P1's 7) before
//    P3's reads OK; cvt loads drained there too, consumed next P1 OK
//  - convert-hoist blocked by per-phase sched_barrier(0) walls (rule 18)
// Xb lives at ws+96MB (no alias with live Ub/VtT); gated on
// ws_size >= 160MB, else the r12 sequential path runs unchanged.
// =====================================================================
#define MM(a, b, c) __builtin_amdgcn_mfma_f32_16x16x32_bf16(a, b, c, 0, 0, 0)

#define ARG(r) (As + (r) * 8192)
#define BRG(r) (Bs + (r) * 8192)

#define STAGE_A(r, koff) do { \
    const unsigned short* _s = A + gAr + (koff); \
    unsigned short* _d = ARG(r) + wave * 512; \
    GLD16(_s, _d); GLD16(_s + (long)128 * K, _d + 4096); } while (0)

#define STAGE_B(r, koff) do { \
    const unsigned short* _s = B + gBr + (koff); \
    unsigned short* _d = BRG(r) + wave * 512; \
    GLD16(_s, _d); GLD16(_s + (long)128 * K, _d + 4096); } while (0)

// inline-asm ds_read_b128, volatile, no "memory" clobber (r11)
#define DSR(dst, base, imm) \
    asm volatile("ds_read_b128 %0, %1 offset:%c2" \
                 : "=v"(dst) : "v"(base), "i"(imm))

#define READ_AB(bk, R) do { \
    DSR(aB[bk][0][0], aByte, (R)*16384 + 0);            \
    DSR(aB[bk][0][1], aByte, (R)*16384 + 1024);         \
    DSR(aB[bk][0][2], aByte, (R)*16384 + 2048);         \
    DSR(aB[bk][0][3], aByte, (R)*16384 + 3072);         \
    DSR(aB[bk][1][0], aByte, (R)*16384 + 4096);         \
    DSR(aB[bk][1][1], aByte, (R)*16384 + 5120);         \
    DSR(aB[bk][1][2], aByte, (R)*16384 + 6144);         \
    DSR(aB[bk][1][3], aByte, (R)*16384 + 7168);         \
    DSR(bB[bk][0],    bByte, (R)*16384 + 0);            \
    DSR(bB[bk][1],    bByte, (R)*16384 + 1024);         \
    DSR(bB[bk][2],    bByte, (R)*16384 + 2048);         \
    DSR(bB[bk][3],    bByte, (R)*16384 + 3072); } while (0)

#define MFMA32(bk) do { \
    _Pragma("unroll") \
    for (int _h = 0; _h < 2; ++_h) \
    _Pragma("unroll") \
    for (int _m = 0; _m < 4; ++_m) { \
        acc[_h*4+_m][0] = MM(aB[bk][_h][_m], bB[bk][0], acc[_h*4+_m][0]); \
        acc[_h*4+_m][1] = MM(aB[bk][_h][_m], bB[bk][1], acc[_h*4+_m][1]); \
        acc[_h*4+_m][2] = MM(aB[bk][_h][_m], bB[bk][2], acc[_h*4+_m][2]); \
        acc[_h*4+_m][3] = MM(aB[bk][_h][_m], bB[bk][3], acc[_h*4+_m][3]); \
    } } while (0)

#define SGB __builtin_amdgcn_sched_group_barrier

#define SGB_PATTERN do { \
    _Pragma("unroll") \
    for (int _g = 0; _g < 12; ++_g) { SGB(0x008, 2, 0); SGB(0x100, 1, 0); } \
    SGB(0x008, 8, 0); } while (0)

#define PHASE(rN, sb, rS, sk, cb) do { \
    STAGE_A(rS, sk); STAGE_B(rS, sk); \
    asm volatile("s_waitcnt lgkmcnt(0)" ::: "memory"); \
    __builtin_amdgcn_sched_barrier(0); \
    __builtin_amdgcn_s_setprio(1); \
    READ_AB(sb, rN); \
    MFMA32(cb); \
    SGB_PATTERN; \
    __builtin_amdgcn_s_setprio(0); \
    asm volatile("s_waitcnt vmcnt(4)" ::: "memory"); \
    __builtin_amdgcn_s_barrier(); } while (0)

#define XCVT_STORE do { \
    union { uint4 v; unsigned short s[8]; } _o; \
    _Pragma("unroll") \
    for (int _j = 0; _j < 4; ++_j) { \
        _o.s[_j]     = f2bf(xv0[_j]); \
        _o.s[_j + 4] = f2bf(xv1[_j]); } \
    *reinterpret_cast<uint4*>((uintptr_t)xsaddr) = _o.v; \
    xsaddr += 2097152ull; } while (0)

template<int OUT_BF16, int BIAS, int DO_CVT>
__global__ __launch_bounds__(512, 2) void gemm256_kernel(
    const unsigned short* __restrict__ A,   // [M][K] bf16 bits
    const unsigned short* __restrict__ B,   // [N][K] bf16 bits
    void* __restrict__ Cv, const float* __restrict__ bias,
    const float* __restrict__ xsrc, unsigned short* __restrict__ xdst,
    int M, int N, int K) {
    __shared__ unsigned short As[4 * 8192];   // 64 KB
    __shared__ unsigned short Bs[4 * 8192];   // 64 KB

    const int tid  = threadIdx.x;
    const int wave = tid >> 6;
    const int lane = tid & 63;
    const int fr   = lane & 15;
    const int fq   = lane >> 4;

    // XCD-aware bijective swizzle + n-pair clustering (r12)
    const int nwg = gridDim.x;
    const int bid = blockIdx.x;
    const int cpx = nwg >> 3;
    const int wg  = (bid & 7) * cpx + (bid >> 3);
    const int nmt = M >> 8;
    const long n0 = (long)(2 * (wg / cpx) + (wg & 1)) << 8;
    const long m0 = (long)((wg >> 1) & (nmt - 1)) << 8;

    const int wwr = wave >> 2;   // 0..1  (M half)
    const int wwc = wave & 3;    // 0..3  (N quarter)

    // Stage addressing (verified): region chunk [256 rows][32 k] bf16,
    // 1024 16B slots; global src slot = (si&3) ^ ((row>>1)&3).
    const int  rS  = tid >> 2;                        // rows rS and rS+128
    const int  sS  = (tid & 3) ^ ((rS >> 1) & 3);
    const long gAr = (m0 + rS) * K + sS * 8;
    const long gBr = (n0 + rS) * K + sS * 8;

    // ds_read (swizzled): elem = row*32 + ((fq ^ ((row>>1)&3))*8)
    const int swz   = (fq ^ ((fr >> 1) & 3)) * 8;
    const int aBase = (wwr * 128 + fr) * 32 + swz;
    const int bBase = (wwc * 64 + fr) * 32 + swz;
    const unsigned aByte = (unsigned)(uintptr_t)(As + aBase);
    const unsigned bByte = (unsigned)(uintptr_t)(Bs + bBase);

    f32x4  acc[8][4] = {};
    short8v aB[2][2][4], bB[2][4];

    // cvt weave state (GEMM1 only): 1 chunk of 8 f32 per thread per iter.
    f32x4 xv0, xv1;
    unsigned long long xaddr = 0, xsaddr = 0;
    if constexpr (DO_CVT) {
        long gchunk = ((long)bid * 512 + tid);
        xaddr  = (unsigned long long)(uintptr_t)(xsrc + gchunk * 8);
        xsaddr = (unsigned long long)(uintptr_t)(xdst + gchunk * 8);
    }

    // Prologue: stage r0@k0, r1@k32, r2@k64; vmcnt(4) confirms r0,r1
    // (r2 confirmed by t=0's P1-end wait); read r0 -> bank0.
    STAGE_A(0, 0);  STAGE_B(0, 0);
    STAGE_A(1, 32); STAGE_B(1, 32);
    STAGE_A(2, 64); STAGE_B(2, 64);
    asm volatile("s_waitcnt vmcnt(4)" ::: "memory");
    __builtin_amdgcn_s_barrier();
    READ_AB(0, 0);

    const int nIter = K >> 7;   // 4 phases x K=32 per iteration
    for (int i = 0; i < nIter; ++i) {
        const int kA = 128 * i + 96;                    // in-bounds
        int k0n = 128 * i + 128; if (k0n >= K) k0n -= K; // wrap: dead
        int k1n = 128 * i + 160; if (k1n >= K) k1n -= K;
        int k2n = 128 * i + 192; if (k2n >= K) k2n -= K;

        if constexpr (DO_CVT) {
            // P1 with cvt weave: store chunk i-1, load chunk i.
            if (i) XCVT_STORE;
            asm volatile("global_load_dwordx4 %0, %2, off\n\t"
                         "global_load_dwordx4 %1, %2, off offset:16"
                         : "=&v"(xv0), "=&v"(xv1) : "v"(xaddr));
            xaddr += 4194304ull;
            STAGE_A(3, kA); STAGE_B(3, kA);
            asm volatile("s_waitcnt lgkmcnt(0)" ::: "memory");
            __builtin_amdgcn_sched_barrier(0);
            __builtin_amdgcn_s_setprio(1);
            READ_AB(1, 1);
            MFMA32(0);
            SGB_PATTERN;
            __builtin_amdgcn_s_setprio(0);
            if (i) asm volatile("s_waitcnt vmcnt(7)" ::: "memory");
            else   asm volatile("s_waitcnt vmcnt(6)" ::: "memory");
            __builtin_amdgcn_s_barrier();
        } else {
            PHASE(1, 1, 3, kA,  0);   // t0: read r1->b1, stage r3, mfma b0
        }
        PHASE(2, 0, 0, k0n, 1);       // t1: read r2->b0, stage r0, mfma b1
        PHASE(3, 1, 1, k1n, 0);       // t2: read r3->b1, stage r1, mfma b0
        PHASE(0, 0, 2, k2n, 1);       // t3: read r0->b0, stage r2, mfma b1
    }

    if constexpr (DO_CVT) XCVT_STORE;   // chunk nIter-1 (loads long drained)

    // Epilogue: C/D layout col = lane&15, row = (lane>>4)*4 + j
#pragma unroll
    for (int nf = 0; nf < 4; ++nf) {
        const int col = (int)n0 + wwc * 64 + nf * 16 + fr;
        float bv = BIAS ? bias[col] : 0.0f;
#pragma unroll
        for (int mf = 0; mf < 8; ++mf) {
            f32x4 v = acc[mf][nf];
            long rowb = m0 + wwr * 128 + mf * 16 + fq * 4;
#pragma unroll
            for (int j = 0; j < 4; ++j) {
                float val = v[j] + bv;
                long off = (rowb + j) * N + col;
                if (OUT_BF16) ((unsigned short*)Cv)[off] = f2bf(val);
                else          ((float*)Cv)[off] = val;
            }
        }
    }
}

extern "C" void kernel_launch(void* const* d_in, const int* in_sizes, int n_in,
                              void* d_out, int out_size, void* d_ws, size_t ws_size,
                              hipStream_t stream) {
    const float* x    = (const float*)d_in[0];   // [4,2048,4096] = [8192][4096]
    const float* U    = (const float*)d_in[1];   // [4096][4096]
    const float* S    = (const float*)d_in[2];   // [4096]
    const float* Vt   = (const float*)d_in[3];   // [4096][4096]
    const float* eps  = (const float*)d_in[4];   // [4096]
    const float* bias = (const float*)d_in[5];   // [4096]
    float* out = (float*)d_out;                  // [8192][4096] fp32

    char* ws = (char*)d_ws;
    unsigned short* Ub  = (unsigned short*)(ws);                       // 32 MB
    unsigned short* VtT = (unsigned short*)(ws + (size_t)(32 << 20));  // 32 MB
    unsigned short* Wb  = (unsigned short*)(ws + (size_t)(64 << 20));  // 32 MB

    // 1) Ub = bf16(U*(S+eps)) ; VtT = bf16(Vt^T)   (fused, independent)
    prep_fused_kernel<<<12288, 256, 0, stream>>>(U, S, eps, Ub, Vt, VtT);

    if (ws_size >= ((size_t)160 << 20)) {
        // Fused path: GEMM1 also streams x -> Xb (at ws+96MB, no alias).
        unsigned short* Xb = (unsigned short*)(ws + ((size_t)96 << 20));
        gemm256_kernel<1, 0, 1><<<256, 512, 0, stream>>>(
            Ub, VtT, (void*)Wb, nullptr, x, Xb, 4096, 4096, 4096);
        gemm256_kernel<0, 1, 0><<<512, 512, 0, stream>>>(
            Xb, Wb, (void*)out, bias, nullptr, nullptr, 8192, 4096, 4096);
    } else {
        // Fallback (r12-identical): sequential cvt, Xb over Ub/VtT.
        unsigned short* Xb = (unsigned short*)(ws);
        gemm256_kernel<1, 0, 0><<<256, 512, 0, stream>>>(
            Ub, VtT, (void*)Wb, nullptr, nullptr, nullptr, 4096, 4096, 4096);
        cvt_bf16_kernel<<<16384, 256, 0, stream>>>(x, Xb);
        gemm256_kernel<0, 1, 0><<<512, 512, 0, stream>>>(
            Xb, Wb, (void*)out, bias, nullptr, nullptr, 8192, 4096, 4096);
    }
}